// Round 7
// baseline (474.360 us; speedup 1.0000x reference)
//
#include <hip/hip_runtime.h>
#include <math.h>

namespace {

typedef _Float16 half8v __attribute__((ext_vector_type(8)));
typedef _Float16 half4v __attribute__((ext_vector_type(4)));
typedef float    floatx4 __attribute__((ext_vector_type(4)));

constexpr int B   = 8;
constexpr int C   = 256;
constexpr int NH  = 4;
constexpr int HD  = 64;
constexpr int NWIN = 400;   // 20x20 windows per level
constexpr int NT  = 35;     // 25 + 9 + 1 tokens per window
constexpr int QKVN = 768;
constexpr int RPB = NWIN * NT;  // 14,000 token-rows per batch

// per-batch byte counts for workspace
constexpr size_t QKV_B  = (size_t)8400 * QKVN * 2;   // 12,902,400  (f16)
constexpr size_t OATT_B = (size_t)RPB * C * 2;       //  7,168,000  (f16)
constexpr size_t YT_B   = (size_t)RPB * C * 4;       // 14,336,000  (f32)
constexpr size_t PB_B   = QKV_B + OATT_B + YT_B;     // 34,406,400
constexpr size_t WT_B   = (size_t)3 * QKVN * C * 2;  //  1,179,648  (f16 transposed W)
constexpr size_t POS_B  = 19712;                     // 4900 f32, padded

// ---------------- pos table ----------------
__device__ inline void token_coord(int j, double& cy, double& cx) {
  if (j < 25)      { int ty = j / 5,  tx = j % 5;  cy = (double)(ty - 2); cx = (double)(tx - 2); }
  else if (j < 34) { int t = j - 25; int ty = t / 3, tx = t % 3;
                     cy = (double)(ty - 1) * (5.0 / 3.0); cx = (double)(tx - 1) * (5.0 / 3.0); }
  else             { cy = 0.0; cx = 0.0; }
}

__global__ void pos_kernel(const float* __restrict__ rpb, const float* __restrict__ ab,
                           float* __restrict__ pos) {
  int p = blockIdx.x * blockDim.x + threadIdx.x;
  if (p >= NH * NT * NT) return;
  int j = p % NT, i = (p / NT) % NT, h = p / (NT * NT);
  double cyi, cxi, cyj, cxj;
  token_coord(i, cyi, cxi);
  token_coord(j, cyj, cxj);
  float fidx = (float)(((cyi - cyj) + 4.0) * 9.0 + ((cxi - cxj) + 4.0));
  int fl = min(max((int)floorf(fidx), 0), 80);
  int ce = min(max((int)ceilf(fidx), 0), 80);
  float w = fidx - (float)fl;
  float pv = (1.0f - w) * rpb[fl * NH + h] + w * rpb[ce * NH + h];
  int li = (i < 25) ? 0 : ((i < 34) ? 1 : 2);
  pos[p] = pv + ab[li * NH + h];
}

// ---------------- W transpose (once per launch): [256][768] f32 -> [768][256] f16 x3 ----------
__global__ __launch_bounds__(256) void wt_kernel(const float* __restrict__ w0,
                                                 const float* __restrict__ w1,
                                                 const float* __restrict__ w2,
                                                 _Float16* __restrict__ wt) {
  const int bx = blockIdx.x;                 // 36 blocks: 12 per W
  const float* src = bx < 12 ? w0 : (bx < 24 ? w1 : w2);
  _Float16* dst = wt + (size_t)(bx / 12) * QKVN * C;
  const int m0 = (bx % 12) * 64;             // output-row (n) range
  __shared__ _Float16 t[64][264];
  const int tid = threadIdx.x;
  const int p4 = (tid & 15) * 4;
#pragma unroll
  for (int it = 0; it < 16; ++it) {
    int c = it * 16 + (tid >> 4);
    floatx4 v = *(const floatx4*)(src + (size_t)c * QKVN + m0 + p4);
#pragma unroll
    for (int i = 0; i < 4; ++i) t[p4 + i][c] = (_Float16)v[i];
  }
  __syncthreads();
#pragma unroll
  for (int e0 = 0; e0 < 8; ++e0) {
    int e = e0 * 256 + tid;
    int p = e >> 5, c8 = e & 31;
    *(half8v*)(dst + (size_t)(m0 + p) * C + c8 * 8) = *(const half8v*)&t[p][c8 * 8];
  }
}

// ---------------- fused QKV GEMM: persistent-A, n-loop inside ----------------
// Block owns one 128-row m-tile; A ([128][256] f16, row stride 264) staged ONCE from the
// original [C][HW] f32 layout (lane owns a row: 8-strided dword reads -> contiguous b128
// LDS write, conflict-free round-2 pattern). Loops 6 n-tiles of 128, staging B (Wt f16,
// L2-resident) per K-step with reg-prefetch. Global A traffic cut 6x; no X transpose pass.
// Epilogue per n-tile: L2-normalize per 64-col head section when n0 < 512 (q,k).
__global__ __launch_bounds__(256) void qkv_gemm(const float* __restrict__ X0,
                                                const float* __restrict__ X1,
                                                const float* __restrict__ X2,
                                                const _Float16* __restrict__ Wt,
                                                _Float16* __restrict__ Y0,
                                                _Float16* __restrict__ Y1,
                                                _Float16* __restrict__ Y2,
                                                int mb0, int mb01, int g) {
  __shared__ _Float16 As[128][264];   // 67.6 KB; rows 16B-aligned, stride 132 words
  __shared__ _Float16 Bs[128][40];

  int mblk = blockIdx.x;
  const float* X; const _Float16* WtL; _Float16* Y; int HW;
  if (mblk < mb0)       { X = X0; WtL = Wt;                 Y = Y0; HW = 6400; }
  else if (mblk < mb01) { X = X1; WtL = Wt + QKVN * C;      Y = Y1; HW = 1600; mblk -= mb0; }
  else                  { X = X2; WtL = Wt + 2 * QKVN * C;  Y = Y2; HW =  400; mblk -= mb01; }
  const int Mg = g * HW;

  const int tid  = threadIdx.x;
  const int m0   = mblk * 128;
  const int w    = tid >> 6;
  const int lane = tid & 63;
  const int quad = lane >> 4;
  const int mn   = lane & 15;

  // ---- stage A once: lane owns row (tid&127), covers k-octs (tid>>7)+2i
  {
    const int r  = tid & 127;
    const int ob = tid >> 7;
    int gm = min(m0 + r, Mg - 1);
    int bb = gm / HW, pix = gm - bb * HW;
    const float* xb = X + (size_t)bb * C * HW + pix;
#pragma unroll
    for (int i = 0; i < 16; ++i) {
      int oct = ob + 2 * i;
      const float* xp = xb + (size_t)oct * 8 * HW;
      half8v hv;
#pragma unroll
      for (int j = 0; j < 8; ++j) hv[j] = (_Float16)xp[(size_t)j * HW];
      *(half8v*)&As[r][oct * 8] = hv;
    }
  }

  // B staging geometry: 512 b128 chunks = 128 n-rows x 4 k-octs, 2 per thread
  int rr[2], k8[2];
#pragma unroll
  for (int u = 0; u < 2; ++u) { int e = u * 256 + tid; rr[u] = e >> 2; k8[u] = e & 3; }

  half8v bpre[2];
  auto PLOAD = [&](int nt, int k0) {
#pragma unroll
    for (int u = 0; u < 2; ++u)
      bpre[u] = *(const half8v*)(WtL + (size_t)(nt * 128 + rr[u]) * C + k8[u] * 8 + k0);
  };

  PLOAD(0, 0);
  __syncthreads();   // As visible to all waves

  for (int nt = 0; nt < 6; ++nt) {
    floatx4 acc[2][8] = {};
    for (int k0 = 0; k0 < C; k0 += 32) {
#pragma unroll
      for (int u = 0; u < 2; ++u) *(half8v*)&Bs[rr[u]][k8[u] * 8] = bpre[u];
      __syncthreads();
      int nk = k0 + 32, nn = nt;
      if (nk == C) { nk = 0; nn = nt + 1; }
      if (nn < 6) PLOAD(nn, nk);   // prefetch next B chunk under MFMA
      half8v a0 = *(const half8v*)&As[w * 32 + mn][k0 + quad * 8];
      half8v a1 = *(const half8v*)&As[w * 32 + 16 + mn][k0 + quad * 8];
#pragma unroll
      for (int ni = 0; ni < 8; ++ni) {
        half8v bf = *(const half8v*)&Bs[ni * 16 + mn][quad * 8];
        acc[0][ni] = __builtin_amdgcn_mfma_f32_16x16x32_f16(a0, bf, acc[0][ni], 0, 0, 0);
        acc[1][ni] = __builtin_amdgcn_mfma_f32_16x16x32_f16(a1, bf, acc[1][ni], 0, 0, 0);
      }
      __syncthreads();
    }

    // epilogue for this n-tile
    const int n0 = nt * 128;
    const bool do_norm = (n0 < 512);
#pragma unroll
    for (int mi = 0; mi < 2; ++mi) {
#pragma unroll
      for (int r = 0; r < 4; ++r) {
        float s0 = 0.f, s1 = 0.f;
#pragma unroll
        for (int ni = 0; ni < 4; ++ni) { float vv = acc[mi][ni][r]; s0 += vv * vv; }
#pragma unroll
        for (int ni = 4; ni < 8; ++ni) { float vv = acc[mi][ni][r]; s1 += vv * vv; }
        s0 += __shfl_xor(s0, 1); s1 += __shfl_xor(s1, 1);
        s0 += __shfl_xor(s0, 2); s1 += __shfl_xor(s1, 2);
        s0 += __shfl_xor(s0, 4); s1 += __shfl_xor(s1, 4);
        s0 += __shfl_xor(s0, 8); s1 += __shfl_xor(s1, 8);
        float sc0 = do_norm ? (1.f / fmaxf(sqrtf(s0), 1e-12f)) : 1.f;
        float sc1 = do_norm ? (1.f / fmaxf(sqrtf(s1), 1e-12f)) : 1.f;
        int row = m0 + w * 32 + mi * 16 + quad * 4 + r;
        if (row < Mg) {
#pragma unroll
          for (int ni = 0; ni < 8; ++ni)
            Y[(size_t)row * QKVN + n0 + ni * 16 + mn] =
                (_Float16)(acc[mi][ni][r] * (ni < 4 ? sc0 : sc1));
        }
      }
    }
  }
}

// ---------------- attention: swapped-operand MFMA version. Block = (b, window); wave = head. ----------------
__device__ inline const _Float16* token_row_ptr(int j, int wy, int wx, int b,
                                                const _Float16* q0, const _Float16* q1,
                                                const _Float16* q2) {
  if (j >= NT) return nullptr;
  int k_, s_, p_, Hl, t; const _Float16* base;
  if (j < 25)      { k_ = 5; s_ = 4; p_ = 2; Hl = 80; t = j;      base = q0; }
  else if (j < 34) { k_ = 3; s_ = 2; p_ = 1; Hl = 40; t = j - 25; base = q1; }
  else             { k_ = 1; s_ = 1; p_ = 0; Hl = 20; t = 0;      base = q2; }
  int ty = t / k_, tx = t % k_;
  int y = wy * s_ + ty - p_;
  int x = wx * s_ + tx - p_;
  if ((unsigned)y >= (unsigned)Hl || (unsigned)x >= (unsigned)Hl) return nullptr;
  return base + ((size_t)b * Hl * Hl + (size_t)y * Hl + x) * QKVN;
}

__global__ __launch_bounds__(256, 4) void attn_kernel(const _Float16* __restrict__ qkv0,
                                                      const _Float16* __restrict__ qkv1,
                                                      const _Float16* __restrict__ qkv2,
                                                      const float* __restrict__ pos,
                                                      _Float16* __restrict__ O) {
  const int blk = blockIdx.x;               // b*NWIN + w
  const int w   = blk % NWIN;
  const int b   = blk / NWIN;
  const int wy = w / 20, wx = w % 20;
  const int tid  = threadIdx.x;
  const int h    = tid >> 6;                // wave = head
  const int lane = tid & 63;
  const int i16  = lane & 15;
  const int q4   = lane >> 4;

  __shared__ __align__(16) _Float16 vrows[48][260];   // V row-major, all heads; rows 35..47 zero

  // --- cooperative V staging: 1536 half8-chunks = 48 rows x 32 chunks over 256 threads
#pragma unroll
  for (int e0 = 0; e0 < 1536; e0 += 256) {
    int e = e0 + tid;
    int j = e >> 5, cc = e & 31;
    half8v val = (half8v)(_Float16)0.f;
    if (j < NT) {
      const _Float16* rp = token_row_ptr(j, wy, wx, b, qkv0, qkv1, qkv2);
      if (rp) val = *(const half8v*)(rp + 512 + cc * 8);
    }
    *(half8v*)&vrows[j][cc * 8] = val;
  }

  // --- Q/K fragments direct from global: tile t rows = tokens t*16 + i16
  half8v qf[3][2], kf[3][2];
#pragma unroll
  for (int t = 0; t < 3; ++t) {
    const _Float16* rp = token_row_ptr(t * 16 + i16, wy, wx, b, qkv0, qkv1, qkv2);
#pragma unroll
    for (int kc = 0; kc < 2; ++kc) {
      if (rp) {
        qf[t][kc] = *(const half8v*)(rp + h * HD + kc * 32 + q4 * 8);
        kf[t][kc] = *(const half8v*)(rp + 256 + h * HD + kc * 32 + q4 * 8);
      } else {
        qf[t][kc] = (half8v)(_Float16)0.f;
        kf[t][kc] = (half8v)(_Float16)0.f;
      }
    }
  }

  // --- swapped QK^T: s[tj][ti][r] = S^T[j=tj*16+q4*4+r][i=ti*16+i16]
  floatx4 s[3][3] = {};
#pragma unroll
  for (int kc = 0; kc < 2; ++kc)
#pragma unroll
    for (int tj = 0; tj < 3; ++tj)
#pragma unroll
      for (int ti = 0; ti < 3; ++ti)
        s[tj][ti] = __builtin_amdgcn_mfma_f32_16x16x32_f16(kf[tj][kc], qf[ti][kc], s[tj][ti], 0, 0, 0);

  // --- pos bias + tile-pad mask (j >= NT -> -inf; tj=0 rows are never masked so max stays finite)
#pragma unroll
  for (int tj = 0; tj < 3; ++tj)
#pragma unroll
    for (int ti = 0; ti < 3; ++ti)
#pragma unroll
      for (int r = 0; r < 4; ++r) {
        int j = tj * 16 + q4 * 4 + r;
        int i = ti * 16 + i16;
        if (j < NT) { if (i < NT) s[tj][ti][r] += pos[(h * NT + i) * NT + j]; }
        else s[tj][ti][r] = -INFINITY;
      }

  // --- in-register softmax over j per query i (col i16): 12 local regs + shfl_xor 16/32
  half4v pa[3][3];   // [tj][ti] = A-frag of P for PV (16x16x16 layout)
#pragma unroll
  for (int ti = 0; ti < 3; ++ti) {
    float m = s[0][ti][0];
#pragma unroll
    for (int tj = 0; tj < 3; ++tj)
#pragma unroll
      for (int r = 0; r < 4; ++r) m = fmaxf(m, s[tj][ti][r]);
    m = fmaxf(m, __shfl_xor(m, 16));
    m = fmaxf(m, __shfl_xor(m, 32));
    float sum = 0.f;
#pragma unroll
    for (int tj = 0; tj < 3; ++tj)
#pragma unroll
      for (int r = 0; r < 4; ++r) { float e = expf(s[tj][ti][r] - m); s[tj][ti][r] = e; sum += e; }
    sum += __shfl_xor(sum, 16);
    sum += __shfl_xor(sum, 32);
    float inv = 1.f / sum;
#pragma unroll
    for (int tj = 0; tj < 3; ++tj)
#pragma unroll
      for (int r = 0; r < 4; ++r) pa[tj][ti][r] = (_Float16)(s[tj][ti][r] * inv);
  }

  __syncthreads();   // vrows ready for all waves

  // --- V B-frags for 16x16x16: lane holds V[j=tj*16+q4*4+kk][d=n*16+i16] (this head's cols)
  half4v vb[3][4];
#pragma unroll
  for (int tj = 0; tj < 3; ++tj)
#pragma unroll
    for (int n = 0; n < 4; ++n)
#pragma unroll
      for (int kk = 0; kk < 4; ++kk)
        vb[tj][n][kk] = vrows[tj * 16 + q4 * 4 + kk][h * HD + n * 16 + i16];

  // --- PV: O[i][d] accumulated over 3 j-chunks of 16; C layout row=q4*4+r (i), col=i16 (d)
  const size_t obase = ((size_t)(b * NWIN + w) * NT) * C + h * HD;
#pragma unroll
  for (int ti = 0; ti < 3; ++ti) {
    floatx4 o[4] = {};
#pragma unroll
    for (int tj = 0; tj < 3; ++tj)
#pragma unroll
      for (int n = 0; n < 4; ++n)
        o[n] = __builtin_amdgcn_mfma_f32_16x16x16f16(pa[tj][ti], vb[tj][n], o[n], 0, 0, 0);
#pragma unroll
    for (int r = 0; r < 4; ++r) {
      int i = ti * 16 + q4 * 4 + r;
      if (i < NT) {
#pragma unroll
        for (int n = 0; n < 4; ++n)
          O[obase + (size_t)i * C + n * 16 + i16] = (_Float16)o[n][r];
      }
    }
  }
}

// ---------------- proj GEMM (f16 MFMA, reg-prefetch) + bias, transposed store ----------------
__global__ __launch_bounds__(256) void proj_gemm(const _Float16* __restrict__ A,  // (Mg, 256) f16 row-major
                                                 const float* __restrict__ W,     // (256, 256) row-major
                                                 const float* __restrict__ bias,
                                                 float* __restrict__ Yt, int Mg) {
  __shared__ __align__(16) char smem[128 * 69 * 4];   // max(As+Bs = 15360, Cs = 35328)
  _Float16 (*As)[40] = (_Float16(*)[40])smem;
  _Float16 (*Bs)[40] = (_Float16(*)[40])(smem + 128 * 40 * 2);
  float    (*Cs)[69] = (float(*)[69])smem;

  const int tid  = threadIdx.x;
  const int m0   = blockIdx.x * 128;
  const int n0   = blockIdx.y * 64;
  const int w    = tid >> 6;
  const int lane = tid & 63;
  const int quad = lane >> 4;
  const int mn   = lane & 15;

  int aM[2], aK8[2], aRow[2];
#pragma unroll
  for (int u = 0; u < 2; ++u) {
    int e = u * 256 + tid;           // 512 units: 128 m x 4 k-octs
    aM[u] = e >> 2; aK8[u] = e & 3;
    aRow[u] = min(m0 + aM[u], Mg - 1);
  }

  half8v apre[2]; float bpre[8];
  auto PLOAD = [&](int k0) {
#pragma unroll
    for (int u = 0; u < 2; ++u)
      apre[u] = *(const half8v*)&A[(size_t)aRow[u] * C + k0 + 8 * aK8[u]];
    const float* wp = W + (size_t)(k0 + w * 8) * C + n0 + lane;
#pragma unroll
    for (int j = 0; j < 8; ++j) bpre[j] = wp[(size_t)j * C];
  };

  PLOAD(0);
  floatx4 acc[2][4] = {};
  for (int k0 = 0; k0 < C; k0 += 32) {
#pragma unroll
    for (int u = 0; u < 2; ++u) *(half8v*)&As[aM[u]][8 * aK8[u]] = apre[u];
    {
      half8v hv;
#pragma unroll
      for (int j = 0; j < 8; ++j) hv[j] = (_Float16)bpre[j];
      *(half8v*)&Bs[lane][w * 8] = hv;
    }
    __syncthreads();
    if (k0 + 32 < C) PLOAD(k0 + 32);   // prefetch next K-step under MFMA
    half8v a0 = *(const half8v*)&As[w * 32 + mn][quad * 8];
    half8v a1 = *(const half8v*)&As[w * 32 + 16 + mn][quad * 8];
#pragma unroll
    for (int ni = 0; ni < 4; ++ni) {
      half8v bf = *(const half8v*)&Bs[ni * 16 + mn][quad * 8];
      acc[0][ni] = __builtin_amdgcn_mfma_f32_16x16x32_f16(a0, bf, acc[0][ni], 0, 0, 0);
      acc[1][ni] = __builtin_amdgcn_mfma_f32_16x16x32_f16(a1, bf, acc[1][ni], 0, 0, 0);
    }
    __syncthreads();   // also protects As/Bs before Cs aliasing overwrite
  }

  // epilogue: bias add into Cs, then transposed coalesced store
#pragma unroll
  for (int mi = 0; mi < 2; ++mi)
#pragma unroll
    for (int r = 0; r < 4; ++r)
#pragma unroll
      for (int ni = 0; ni < 4; ++ni)
        Cs[w * 32 + mi * 16 + quad * 4 + r][ni * 16 + mn] =
            acc[mi][ni][r] + bias[n0 + ni * 16 + mn];
  __syncthreads();
#pragma unroll
  for (int u = 0; u < 32; ++u) {
    int e = u * 256 + tid;            // 8192 elems: 128 m x 64 n
    int ml = e & 127, cl = e >> 7;
    int m = m0 + ml;
    if (m < Mg) {
      int bb = m / RPB;
      int r = m - bb * RPB;
      Yt[((size_t)bb * C + n0 + cl) * RPB + r] = Cs[ml][cl];
    }
  }
}

// ---------------- fold (gather form), group-local ----------------
__global__ __launch_bounds__(256) void fold_kernel(const float* __restrict__ Yt,
                                                   float* __restrict__ out,
                                                   int k_, int s_, int p_, int H_,
                                                   int toff, int total) {
  int idx = blockIdx.x * 256 + threadIdx.x;
  if (idx >= total) return;
  int x = idx % H_;
  int y = (idx / H_) % H_;
  int c = (idx / (H_ * H_)) % C;
  int b = idx / (C * H_ * H_);
  int py = y + p_, px = x + p_;
  int ay = py - k_ + 1;
  int wy_lo = ay <= 0 ? 0 : (ay + s_ - 1) / s_;
  int wy_hi = min(19, py / s_);
  int ax = px - k_ + 1;
  int wx_lo = ax <= 0 ? 0 : (ax + s_ - 1) / s_;
  int wx_hi = min(19, px / s_);
  const float* base = Yt + ((size_t)b * C + c) * RPB;
  float acc = 0.f;
  for (int wy = wy_lo; wy <= wy_hi; ++wy) {
    int tyy = py - wy * s_;
    for (int wx = wx_lo; wx <= wx_hi; ++wx) {
      int txx = px - wx * s_;
      acc += base[(wy * 20 + wx) * NT + toff + tyy * k_ + txx];
    }
  }
  out[idx] = acc;
}

} // namespace

extern "C" void kernel_launch(void* const* d_in, const int* in_sizes, int n_in,
                              void* d_out, int out_size, void* d_ws, size_t ws_size,
                              hipStream_t stream) {
  const float* x0    = (const float*)d_in[0];
  const float* x1    = (const float*)d_in[1];
  const float* x2    = (const float*)d_in[2];
  const float* wq0   = (const float*)d_in[3];
  const float* wq1   = (const float*)d_in[4];
  const float* wq2   = (const float*)d_in[5];
  const float* wproj = (const float*)d_in[6];
  const float* bproj = (const float*)d_in[7];
  const float* rpb   = (const float*)d_in[8];
  const float* ab    = (const float*)d_in[9];
  float* out = (float*)d_out;

  // pick largest batch-group size g in {8,4,2,1} that fits ws_size (incl. Wt buffer)
  int g = 8;
  while (g > 1 && POS_B + (size_t)g * PB_B + WT_B > ws_size) g >>= 1;

  char* ws = (char*)d_ws;
  float*    posb  = (float*)ws;
  _Float16* qkv0g = (_Float16*)(ws + POS_B);
  _Float16* qkv1g = qkv0g + (size_t)g * 6400 * QKVN;
  _Float16* qkv2g = qkv1g + (size_t)g * 1600 * QKVN;
  _Float16* oatt  = qkv2g + (size_t)g *  400 * QKVN;
  float*    yt    = (float*)(ws + POS_B + (size_t)g * (QKV_B + OATT_B));
  _Float16* wt    = (_Float16*)(ws + POS_B + (size_t)g * PB_B);

  pos_kernel<<<(NH * NT * NT + 255) / 256, 256, 0, stream>>>(rpb, ab, posb);
  wt_kernel<<<36, 256, 0, stream>>>(wq0, wq1, wq2, wt);

  const size_t off1 = (size_t)B * C * 6400;
  const size_t off2 = off1 + (size_t)B * C * 1600;

  const int mb0 = (g * 6400 + 127) / 128;
  const int mb1 = (g * 1600 + 127) / 128;
  const int mb2 = (g *  400 + 127) / 128;

  for (int b0 = 0; b0 < B; b0 += g) {
    const float* x0g = x0 + (size_t)b0 * C * 6400;
    const float* x1g = x1 + (size_t)b0 * C * 1600;
    const float* x2g = x2 + (size_t)b0 * C * 400;

    qkv_gemm<<<mb0 + mb1 + mb2, 256, 0, stream>>>(
        x0g, x1g, x2g, wt, qkv0g, qkv1g, qkv2g, mb0, mb0 + mb1, g);

    attn_kernel<<<g * NWIN, 256, 0, stream>>>(qkv0g, qkv1g, qkv2g, posb, oatt);

    proj_gemm<<<dim3((g * RPB + 127) / 128, C / 64), 256, 0, stream>>>(oatt, wproj, bproj, yt, g * RPB);

    const int tot0 = g * C * 6400;
    const int tot1 = g * C * 1600;
    const int tot2 = g * C * 400;
    fold_kernel<<<(tot0 + 255) / 256, 256, 0, stream>>>(yt, out + (size_t)b0 * C * 6400,        5, 4, 2, 80, 0,  tot0);
    fold_kernel<<<(tot1 + 255) / 256, 256, 0, stream>>>(yt, out + off1 + (size_t)b0 * C * 1600, 3, 2, 1, 40, 25, tot1);
    fold_kernel<<<(tot2 + 255) / 256, 256, 0, stream>>>(yt, out + off2 + (size_t)b0 * C * 400,  1, 1, 0, 20, 34, tot2);
  }
}

// Round 8
// 468.554 us; speedup vs baseline: 1.0124x; 1.0124x over previous
//
#include <hip/hip_runtime.h>
#include <math.h>

namespace {

typedef _Float16 half8v __attribute__((ext_vector_type(8)));
typedef _Float16 half4v __attribute__((ext_vector_type(4)));
typedef float    floatx4 __attribute__((ext_vector_type(4)));

constexpr int B   = 8;
constexpr int C   = 256;
constexpr int NH  = 4;
constexpr int HD  = 64;
constexpr int NWIN = 400;   // 20x20 windows per level
constexpr int NT  = 35;     // 25 + 9 + 1 tokens per window
constexpr int QKVN = 768;
constexpr int RPB = NWIN * NT;  // 14,000 token-rows per batch

// per-batch byte counts for workspace
constexpr size_t QKV_B  = (size_t)8400 * QKVN * 2;   // 12,902,400  (f16)
constexpr size_t OATT_B = (size_t)RPB * C * 2;       //  7,168,000  (f16)
constexpr size_t YT_B   = (size_t)RPB * C * 4;       // 14,336,000  (f32)
constexpr size_t PB_B   = QKV_B + OATT_B + YT_B;     // 34,406,400
constexpr size_t WT_B   = (size_t)3 * QKVN * C * 2;  //  1,179,648  (f16 transposed W)
constexpr size_t POS_B  = 19712;                     // 4900 f32, padded

// ---------------- pos table ----------------
__device__ inline void token_coord(int j, double& cy, double& cx) {
  if (j < 25)      { int ty = j / 5,  tx = j % 5;  cy = (double)(ty - 2); cx = (double)(tx - 2); }
  else if (j < 34) { int t = j - 25; int ty = t / 3, tx = t % 3;
                     cy = (double)(ty - 1) * (5.0 / 3.0); cx = (double)(tx - 1) * (5.0 / 3.0); }
  else             { cy = 0.0; cx = 0.0; }
}

__global__ void pos_kernel(const float* __restrict__ rpb, const float* __restrict__ ab,
                           float* __restrict__ pos) {
  int p = blockIdx.x * blockDim.x + threadIdx.x;
  if (p >= NH * NT * NT) return;
  int j = p % NT, i = (p / NT) % NT, h = p / (NT * NT);
  double cyi, cxi, cyj, cxj;
  token_coord(i, cyi, cxi);
  token_coord(j, cyj, cxj);
  float fidx = (float)(((cyi - cyj) + 4.0) * 9.0 + ((cxi - cxj) + 4.0));
  int fl = min(max((int)floorf(fidx), 0), 80);
  int ce = min(max((int)ceilf(fidx), 0), 80);
  float w = fidx - (float)fl;
  float pv = (1.0f - w) * rpb[fl * NH + h] + w * rpb[ce * NH + h];
  int li = (i < 25) ? 0 : ((i < 34) ? 1 : 2);
  pos[p] = pv + ab[li * NH + h];
}

// ---------------- W transpose (once per launch): [256][768] f32 -> [768][256] f16 x3 ----------
__global__ __launch_bounds__(256) void wt_kernel(const float* __restrict__ w0,
                                                 const float* __restrict__ w1,
                                                 const float* __restrict__ w2,
                                                 _Float16* __restrict__ wt) {
  const int bx = blockIdx.x;                 // 36 blocks: 12 per W
  const float* src = bx < 12 ? w0 : (bx < 24 ? w1 : w2);
  _Float16* dst = wt + (size_t)(bx / 12) * QKVN * C;
  const int m0 = (bx % 12) * 64;             // output-row (n) range
  __shared__ _Float16 t[64][264];
  const int tid = threadIdx.x;
  const int p4 = (tid & 15) * 4;
#pragma unroll
  for (int it = 0; it < 16; ++it) {
    int c = it * 16 + (tid >> 4);
    floatx4 v = *(const floatx4*)(src + (size_t)c * QKVN + m0 + p4);
#pragma unroll
    for (int i = 0; i < 4; ++i) t[p4 + i][c] = (_Float16)v[i];
  }
  __syncthreads();
#pragma unroll
  for (int e0 = 0; e0 < 8; ++e0) {
    int e = e0 * 256 + tid;
    int p = e >> 5, c8 = e & 31;
    *(half8v*)(dst + (size_t)(m0 + p) * C + c8 * 8) = *(const half8v*)&t[p][c8 * 8];
  }
}

// ---------------- fused QKV GEMM: persistent-A (64-row tile), n-split 2, B double-buffer ----
// Block = (ny, mblk): stages A ([64][256] f16) once from raw [C][HW] f32 X, then 3 n-tiles
// x 8 K-steps with ONE barrier per step (Bs double-buffered; write-next + prefetch-issue
// precede the MFMAs). Grid (2, mblks) so the two A-sharing blocks are linear-adjacent
// (same XCD -> 2nd A read hits L2). LDS 54.3 KB -> 2 blocks/CU.
__global__ __launch_bounds__(256) void qkv_gemm(const float* __restrict__ X0,
                                                const float* __restrict__ X1,
                                                const float* __restrict__ X2,
                                                const _Float16* __restrict__ Wt,
                                                _Float16* __restrict__ Y0,
                                                _Float16* __restrict__ Y1,
                                                _Float16* __restrict__ Y2,
                                                int mb0, int mb01, int g) {
  __shared__ _Float16 As[64][264];      // 33.8 KB
  __shared__ _Float16 Bs[2][128][40];   // 20.5 KB

  int mblk = blockIdx.y;
  const int ny = blockIdx.x;            // n-half: tiles ny*3 .. ny*3+2
  const float* X; const _Float16* WtL; _Float16* Y; int HW;
  if (mblk < mb0)       { X = X0; WtL = Wt;                 Y = Y0; HW = 6400; }
  else if (mblk < mb01) { X = X1; WtL = Wt + QKVN * C;      Y = Y1; HW = 1600; mblk -= mb0; }
  else                  { X = X2; WtL = Wt + 2 * QKVN * C;  Y = Y2; HW =  400; mblk -= mb01; }
  const int Mg = g * HW;

  const int tid  = threadIdx.x;
  const int m0   = mblk * 64;
  const int w    = tid >> 6;
  const int lane = tid & 63;
  const int quad = lane >> 4;
  const int mn   = lane & 15;

  // ---- stage A once: thread owns row (tid&63), k-octs (tid>>6)+4i
  {
    const int r  = tid & 63;
    const int ob = tid >> 6;
    int gm = min(m0 + r, Mg - 1);
    int bb = gm / HW, pix = gm - bb * HW;
    const float* xb = X + (size_t)bb * C * HW + pix;
#pragma unroll
    for (int i = 0; i < 8; ++i) {
      int oct = ob + 4 * i;
      const float* xp = xb + (size_t)oct * 8 * HW;
      half8v hv;
#pragma unroll
      for (int j = 0; j < 8; ++j) hv[j] = (_Float16)xp[(size_t)j * HW];
      *(half8v*)&As[r][oct * 8] = hv;
    }
  }

  // B staging geometry: 512 b128 chunks = 128 n-rows x 4 k-octs, 2 per thread
  int rr[2], k8[2];
#pragma unroll
  for (int u = 0; u < 2; ++u) { int e = u * 256 + tid; rr[u] = e >> 2; k8[u] = e & 3; }

  const int nt0 = ny * 3;
  half8v bpre[2];
  auto PLOAD = [&](int st) {   // st = global step index 0..23 -> (tile, k0)
    int nt = nt0 + (st >> 3);
    int k0 = (st & 7) * 32;
#pragma unroll
    for (int u = 0; u < 2; ++u)
      bpre[u] = *(const half8v*)(WtL + (size_t)(nt * 128 + rr[u]) * C + k8[u] * 8 + k0);
  };

  // prologue: Bs[0] <- step 0; bpre <- step 1
  PLOAD(0);
#pragma unroll
  for (int u = 0; u < 2; ++u) *(half8v*)&Bs[0][rr[u]][k8[u] * 8] = bpre[u];
  PLOAD(1);
  __syncthreads();   // As + Bs[0] visible

  int cur = 0;
  for (int nt = nt0; nt < nt0 + 3; ++nt) {
    floatx4 acc[8] = {};
    for (int k0 = 0; k0 < C; k0 += 32) {
      // write next buffer (bpre = step st+1), then issue step st+2
#pragma unroll
      for (int u = 0; u < 2; ++u) *(half8v*)&Bs[cur ^ 1][rr[u]][k8[u] * 8] = bpre[u];
      int st2 = (nt - nt0) * 8 + (k0 >> 5) + 2;
      if (st2 < 24) PLOAD(st2);
      // compute on Bs[cur]
      half8v a0 = *(const half8v*)&As[w * 16 + mn][k0 + quad * 8];
#pragma unroll
      for (int ni = 0; ni < 8; ++ni) {
        half8v bf = *(const half8v*)&Bs[cur][ni * 16 + mn][quad * 8];
        acc[ni] = __builtin_amdgcn_mfma_f32_16x16x32_f16(a0, bf, acc[ni], 0, 0, 0);
      }
      cur ^= 1;
      __syncthreads();
    }

    // epilogue for this n-tile (regs + global stores only; no barrier needed)
    const int n0 = nt * 128;
    const bool do_norm = (n0 < 512);
#pragma unroll
    for (int r = 0; r < 4; ++r) {
      float s0 = 0.f, s1 = 0.f;
#pragma unroll
      for (int ni = 0; ni < 4; ++ni) { float vv = acc[ni][r]; s0 += vv * vv; }
#pragma unroll
      for (int ni = 4; ni < 8; ++ni) { float vv = acc[ni][r]; s1 += vv * vv; }
      s0 += __shfl_xor(s0, 1); s1 += __shfl_xor(s1, 1);
      s0 += __shfl_xor(s0, 2); s1 += __shfl_xor(s1, 2);
      s0 += __shfl_xor(s0, 4); s1 += __shfl_xor(s1, 4);
      s0 += __shfl_xor(s0, 8); s1 += __shfl_xor(s1, 8);
      float sc0 = do_norm ? (1.f / fmaxf(sqrtf(s0), 1e-12f)) : 1.f;
      float sc1 = do_norm ? (1.f / fmaxf(sqrtf(s1), 1e-12f)) : 1.f;
      int row = m0 + w * 16 + quad * 4 + r;
      if (row < Mg) {
#pragma unroll
        for (int ni = 0; ni < 8; ++ni)
          Y[(size_t)row * QKVN + n0 + ni * 16 + mn] =
              (_Float16)(acc[ni][r] * (ni < 4 ? sc0 : sc1));
      }
    }
  }
}

// ---------------- attention: swapped-operand MFMA version. Block = (b, window); wave = head. ----------------
__device__ inline const _Float16* token_row_ptr(int j, int wy, int wx, int b,
                                                const _Float16* q0, const _Float16* q1,
                                                const _Float16* q2) {
  if (j >= NT) return nullptr;
  int k_, s_, p_, Hl, t; const _Float16* base;
  if (j < 25)      { k_ = 5; s_ = 4; p_ = 2; Hl = 80; t = j;      base = q0; }
  else if (j < 34) { k_ = 3; s_ = 2; p_ = 1; Hl = 40; t = j - 25; base = q1; }
  else             { k_ = 1; s_ = 1; p_ = 0; Hl = 20; t = 0;      base = q2; }
  int ty = t / k_, tx = t % k_;
  int y = wy * s_ + ty - p_;
  int x = wx * s_ + tx - p_;
  if ((unsigned)y >= (unsigned)Hl || (unsigned)x >= (unsigned)Hl) return nullptr;
  return base + ((size_t)b * Hl * Hl + (size_t)y * Hl + x) * QKVN;
}

__global__ __launch_bounds__(256, 4) void attn_kernel(const _Float16* __restrict__ qkv0,
                                                      const _Float16* __restrict__ qkv1,
                                                      const _Float16* __restrict__ qkv2,
                                                      const float* __restrict__ pos,
                                                      _Float16* __restrict__ O) {
  const int blk = blockIdx.x;               // b*NWIN + w
  const int w   = blk % NWIN;
  const int b   = blk / NWIN;
  const int wy = w / 20, wx = w % 20;
  const int tid  = threadIdx.x;
  const int h    = tid >> 6;                // wave = head
  const int lane = tid & 63;
  const int i16  = lane & 15;
  const int q4   = lane >> 4;

  __shared__ __align__(16) _Float16 vrows[48][260];   // V row-major, all heads; rows 35..47 zero

  // --- cooperative V staging: 1536 half8-chunks = 48 rows x 32 chunks over 256 threads
#pragma unroll
  for (int e0 = 0; e0 < 1536; e0 += 256) {
    int e = e0 + tid;
    int j = e >> 5, cc = e & 31;
    half8v val = (half8v)(_Float16)0.f;
    if (j < NT) {
      const _Float16* rp = token_row_ptr(j, wy, wx, b, qkv0, qkv1, qkv2);
      if (rp) val = *(const half8v*)(rp + 512 + cc * 8);
    }
    *(half8v*)&vrows[j][cc * 8] = val;
  }

  // --- Q/K fragments direct from global: tile t rows = tokens t*16 + i16
  half8v qf[3][2], kf[3][2];
#pragma unroll
  for (int t = 0; t < 3; ++t) {
    const _Float16* rp = token_row_ptr(t * 16 + i16, wy, wx, b, qkv0, qkv1, qkv2);
#pragma unroll
    for (int kc = 0; kc < 2; ++kc) {
      if (rp) {
        qf[t][kc] = *(const half8v*)(rp + h * HD + kc * 32 + q4 * 8);
        kf[t][kc] = *(const half8v*)(rp + 256 + h * HD + kc * 32 + q4 * 8);
      } else {
        qf[t][kc] = (half8v)(_Float16)0.f;
        kf[t][kc] = (half8v)(_Float16)0.f;
      }
    }
  }

  // --- swapped QK^T: s[tj][ti][r] = S^T[j=tj*16+q4*4+r][i=ti*16+i16]
  floatx4 s[3][3] = {};
#pragma unroll
  for (int kc = 0; kc < 2; ++kc)
#pragma unroll
    for (int tj = 0; tj < 3; ++tj)
#pragma unroll
      for (int ti = 0; ti < 3; ++ti)
        s[tj][ti] = __builtin_amdgcn_mfma_f32_16x16x32_f16(kf[tj][kc], qf[ti][kc], s[tj][ti], 0, 0, 0);

  // --- pos bias + tile-pad mask (j >= NT -> -inf; tj=0 rows are never masked so max stays finite)
#pragma unroll
  for (int tj = 0; tj < 3; ++tj)
#pragma unroll
    for (int ti = 0; ti < 3; ++ti)
#pragma unroll
      for (int r = 0; r < 4; ++r) {
        int j = tj * 16 + q4 * 4 + r;
        int i = ti * 16 + i16;
        if (j < NT) { if (i < NT) s[tj][ti][r] += pos[(h * NT + i) * NT + j]; }
        else s[tj][ti][r] = -INFINITY;
      }

  // --- in-register softmax over j per query i (col i16): 12 local regs + shfl_xor 16/32
  half4v pa[3][3];   // [tj][ti] = A-frag of P for PV (16x16x16 layout)
#pragma unroll
  for (int ti = 0; ti < 3; ++ti) {
    float m = s[0][ti][0];
#pragma unroll
    for (int tj = 0; tj < 3; ++tj)
#pragma unroll
      for (int r = 0; r < 4; ++r) m = fmaxf(m, s[tj][ti][r]);
    m = fmaxf(m, __shfl_xor(m, 16));
    m = fmaxf(m, __shfl_xor(m, 32));
    float sum = 0.f;
#pragma unroll
    for (int tj = 0; tj < 3; ++tj)
#pragma unroll
      for (int r = 0; r < 4; ++r) { float e = expf(s[tj][ti][r] - m); s[tj][ti][r] = e; sum += e; }
    sum += __shfl_xor(sum, 16);
    sum += __shfl_xor(sum, 32);
    float inv = 1.f / sum;
#pragma unroll
    for (int tj = 0; tj < 3; ++tj)
#pragma unroll
      for (int r = 0; r < 4; ++r) pa[tj][ti][r] = (_Float16)(s[tj][ti][r] * inv);
  }

  __syncthreads();   // vrows ready for all waves

  // --- V B-frags for 16x16x16: lane holds V[j=tj*16+q4*4+kk][d=n*16+i16] (this head's cols)
  half4v vb[3][4];
#pragma unroll
  for (int tj = 0; tj < 3; ++tj)
#pragma unroll
    for (int n = 0; n < 4; ++n)
#pragma unroll
      for (int kk = 0; kk < 4; ++kk)
        vb[tj][n][kk] = vrows[tj * 16 + q4 * 4 + kk][h * HD + n * 16 + i16];

  // --- PV: O[i][d] accumulated over 3 j-chunks of 16; C layout row=q4*4+r (i), col=i16 (d)
  const size_t obase = ((size_t)(b * NWIN + w) * NT) * C + h * HD;
#pragma unroll
  for (int ti = 0; ti < 3; ++ti) {
    floatx4 o[4] = {};
#pragma unroll
    for (int tj = 0; tj < 3; ++tj)
#pragma unroll
      for (int n = 0; n < 4; ++n)
        o[n] = __builtin_amdgcn_mfma_f32_16x16x16f16(pa[tj][ti], vb[tj][n], o[n], 0, 0, 0);
#pragma unroll
    for (int r = 0; r < 4; ++r) {
      int i = ti * 16 + q4 * 4 + r;
      if (i < NT) {
#pragma unroll
        for (int n = 0; n < 4; ++n)
          O[obase + (size_t)i * C + n * 16 + i16] = (_Float16)o[n][r];
      }
    }
  }
}

// ---------------- proj GEMM (f16 MFMA, reg-prefetch) + bias, transposed store ----------------
__global__ __launch_bounds__(256) void proj_gemm(const _Float16* __restrict__ A,  // (Mg, 256) f16 row-major
                                                 const float* __restrict__ W,     // (256, 256) row-major
                                                 const float* __restrict__ bias,
                                                 float* __restrict__ Yt, int Mg) {
  __shared__ __align__(16) char smem[128 * 69 * 4];   // max(As+Bs = 15360, Cs = 35328)
  _Float16 (*As)[40] = (_Float16(*)[40])smem;
  _Float16 (*Bs)[40] = (_Float16(*)[40])(smem + 128 * 40 * 2);
  float    (*Cs)[69] = (float(*)[69])smem;

  const int tid  = threadIdx.x;
  const int m0   = blockIdx.x * 128;
  const int n0   = blockIdx.y * 64;
  const int w    = tid >> 6;
  const int lane = tid & 63;
  const int quad = lane >> 4;
  const int mn   = lane & 15;

  int aM[2], aK8[2], aRow[2];
#pragma unroll
  for (int u = 0; u < 2; ++u) {
    int e = u * 256 + tid;           // 512 units: 128 m x 4 k-octs
    aM[u] = e >> 2; aK8[u] = e & 3;
    aRow[u] = min(m0 + aM[u], Mg - 1);
  }

  half8v apre[2]; float bpre[8];
  auto PLOAD = [&](int k0) {
#pragma unroll
    for (int u = 0; u < 2; ++u)
      apre[u] = *(const half8v*)&A[(size_t)aRow[u] * C + k0 + 8 * aK8[u]];
    const float* wp = W + (size_t)(k0 + w * 8) * C + n0 + lane;
#pragma unroll
    for (int j = 0; j < 8; ++j) bpre[j] = wp[(size_t)j * C];
  };

  PLOAD(0);
  floatx4 acc[2][4] = {};
  for (int k0 = 0; k0 < C; k0 += 32) {
#pragma unroll
    for (int u = 0; u < 2; ++u) *(half8v*)&As[aM[u]][8 * aK8[u]] = apre[u];
    {
      half8v hv;
#pragma unroll
      for (int j = 0; j < 8; ++j) hv[j] = (_Float16)bpre[j];
      *(half8v*)&Bs[lane][w * 8] = hv;
    }
    __syncthreads();
    if (k0 + 32 < C) PLOAD(k0 + 32);   // prefetch next K-step under MFMA
    half8v a0 = *(const half8v*)&As[w * 32 + mn][quad * 8];
    half8v a1 = *(const half8v*)&As[w * 32 + 16 + mn][quad * 8];
#pragma unroll
    for (int ni = 0; ni < 4; ++ni) {
      half8v bf = *(const half8v*)&Bs[ni * 16 + mn][quad * 8];
      acc[0][ni] = __builtin_amdgcn_mfma_f32_16x16x32_f16(a0, bf, acc[0][ni], 0, 0, 0);
      acc[1][ni] = __builtin_amdgcn_mfma_f32_16x16x32_f16(a1, bf, acc[1][ni], 0, 0, 0);
    }
    __syncthreads();   // also protects As/Bs before Cs aliasing overwrite
  }

  // epilogue: bias add into Cs, then transposed coalesced store
#pragma unroll
  for (int mi = 0; mi < 2; ++mi)
#pragma unroll
    for (int r = 0; r < 4; ++r)
#pragma unroll
      for (int ni = 0; ni < 4; ++ni)
        Cs[w * 32 + mi * 16 + quad * 4 + r][ni * 16 + mn] =
            acc[mi][ni][r] + bias[n0 + ni * 16 + mn];
  __syncthreads();
#pragma unroll
  for (int u = 0; u < 32; ++u) {
    int e = u * 256 + tid;            // 8192 elems: 128 m x 64 n
    int ml = e & 127, cl = e >> 7;
    int m = m0 + ml;
    if (m < Mg) {
      int bb = m / RPB;
      int r = m - bb * RPB;
      Yt[((size_t)bb * C + n0 + cl) * RPB + r] = Cs[ml][cl];
    }
  }
}

// ---------------- fold (gather form), group-local ----------------
__global__ __launch_bounds__(256) void fold_kernel(const float* __restrict__ Yt,
                                                   float* __restrict__ out,
                                                   int k_, int s_, int p_, int H_,
                                                   int toff, int total) {
  int idx = blockIdx.x * 256 + threadIdx.x;
  if (idx >= total) return;
  int x = idx % H_;
  int y = (idx / H_) % H_;
  int c = (idx / (H_ * H_)) % C;
  int b = idx / (C * H_ * H_);
  int py = y + p_, px = x + p_;
  int ay = py - k_ + 1;
  int wy_lo = ay <= 0 ? 0 : (ay + s_ - 1) / s_;
  int wy_hi = min(19, py / s_);
  int ax = px - k_ + 1;
  int wx_lo = ax <= 0 ? 0 : (ax + s_ - 1) / s_;
  int wx_hi = min(19, px / s_);
  const float* base = Yt + ((size_t)b * C + c) * RPB;
  float acc = 0.f;
  for (int wy = wy_lo; wy <= wy_hi; ++wy) {
    int tyy = py - wy * s_;
    for (int wx = wx_lo; wx <= wx_hi; ++wx) {
      int txx = px - wx * s_;
      acc += base[(wy * 20 + wx) * NT + toff + tyy * k_ + txx];
    }
  }
  out[idx] = acc;
}

} // namespace

extern "C" void kernel_launch(void* const* d_in, const int* in_sizes, int n_in,
                              void* d_out, int out_size, void* d_ws, size_t ws_size,
                              hipStream_t stream) {
  const float* x0    = (const float*)d_in[0];
  const float* x1    = (const float*)d_in[1];
  const float* x2    = (const float*)d_in[2];
  const float* wq0   = (const float*)d_in[3];
  const float* wq1   = (const float*)d_in[4];
  const float* wq2   = (const float*)d_in[5];
  const float* wproj = (const float*)d_in[6];
  const float* bproj = (const float*)d_in[7];
  const float* rpb   = (const float*)d_in[8];
  const float* ab    = (const float*)d_in[9];
  float* out = (float*)d_out;

  // pick largest batch-group size g in {8,4,2,1} that fits ws_size (incl. Wt buffer)
  int g = 8;
  while (g > 1 && POS_B + (size_t)g * PB_B + WT_B > ws_size) g >>= 1;

  char* ws = (char*)d_ws;
  float*    posb  = (float*)ws;
  _Float16* qkv0g = (_Float16*)(ws + POS_B);
  _Float16* qkv1g = qkv0g + (size_t)g * 6400 * QKVN;
  _Float16* qkv2g = qkv1g + (size_t)g * 1600 * QKVN;
  _Float16* oatt  = qkv2g + (size_t)g *  400 * QKVN;
  float*    yt    = (float*)(ws + POS_B + (size_t)g * (QKV_B + OATT_B));
  _Float16* wt    = (_Float16*)(ws + POS_B + (size_t)g * PB_B);

  pos_kernel<<<(NH * NT * NT + 255) / 256, 256, 0, stream>>>(rpb, ab, posb);
  wt_kernel<<<36, 256, 0, stream>>>(wq0, wq1, wq2, wt);

  const size_t off1 = (size_t)B * C * 6400;
  const size_t off2 = off1 + (size_t)B * C * 1600;

  const int mb0 = (g * 6400 + 63) / 64;
  const int mb1 = (g * 1600 + 63) / 64;
  const int mb2 = (g *  400 + 63) / 64;

  for (int b0 = 0; b0 < B; b0 += g) {
    const float* x0g = x0 + (size_t)b0 * C * 6400;
    const float* x1g = x1 + (size_t)b0 * C * 1600;
    const float* x2g = x2 + (size_t)b0 * C * 400;

    qkv_gemm<<<dim3(2, mb0 + mb1 + mb2), 256, 0, stream>>>(
        x0g, x1g, x2g, wt, qkv0g, qkv1g, qkv2g, mb0, mb0 + mb1, g);

    attn_kernel<<<g * NWIN, 256, 0, stream>>>(qkv0g, qkv1g, qkv2g, posb, oatt);

    proj_gemm<<<dim3((g * RPB + 127) / 128, C / 64), 256, 0, stream>>>(oatt, wproj, bproj, yt, g * RPB);

    const int tot0 = g * C * 6400;
    const int tot1 = g * C * 1600;
    const int tot2 = g * C * 400;
    fold_kernel<<<(tot0 + 255) / 256, 256, 0, stream>>>(yt, out + (size_t)b0 * C * 6400,        5, 4, 2, 80, 0,  tot0);
    fold_kernel<<<(tot1 + 255) / 256, 256, 0, stream>>>(yt, out + off1 + (size_t)b0 * C * 1600, 3, 2, 1, 40, 25, tot1);
    fold_kernel<<<(tot2 + 255) / 256, 256, 0, stream>>>(yt, out + off2 + (size_t)b0 * C * 400,  1, 1, 0, 20, 34, tot2);
  }
}

// Round 9
// 409.292 us; speedup vs baseline: 1.1590x; 1.1448x over previous
//
#include <hip/hip_runtime.h>
#include <math.h>

namespace {

typedef _Float16 half8v __attribute__((ext_vector_type(8)));
typedef _Float16 half4v __attribute__((ext_vector_type(4)));
typedef float    floatx4 __attribute__((ext_vector_type(4)));

constexpr int B   = 8;
constexpr int C   = 256;
constexpr int NH  = 4;
constexpr int HD  = 64;
constexpr int NWIN = 400;   // 20x20 windows per level
constexpr int NT  = 35;     // 25 + 9 + 1 tokens per window
constexpr int QKVN = 768;
constexpr int RPB = NWIN * NT;  // 14,000 token-rows per batch

// per-batch byte counts for workspace
constexpr size_t QKV_B  = (size_t)8400 * QKVN * 2;   // 12,902,400  (f16)
constexpr size_t OATT_B = (size_t)RPB * C * 2;       //  7,168,000  (f16)
constexpr size_t YT_B   = (size_t)RPB * C * 4;       // 14,336,000  (f32)  >= QKV_B
constexpr size_t PBA_B  = YT_B + OATT_B;             // 21,504,000  aliased per-batch
constexpr size_t WT_B   = (size_t)3 * QKVN * C * 2;  //  1,179,648  (f16 transposed W)
constexpr size_t POS_B  = 19712;                     // 4900 f32, padded

// ---------------- pos table ----------------
__device__ inline void token_coord(int j, double& cy, double& cx) {
  if (j < 25)      { int ty = j / 5,  tx = j % 5;  cy = (double)(ty - 2); cx = (double)(tx - 2); }
  else if (j < 34) { int t = j - 25; int ty = t / 3, tx = t % 3;
                     cy = (double)(ty - 1) * (5.0 / 3.0); cx = (double)(tx - 1) * (5.0 / 3.0); }
  else             { cy = 0.0; cx = 0.0; }
}

__global__ void pos_kernel(const float* __restrict__ rpb, const float* __restrict__ ab,
                           float* __restrict__ pos) {
  int p = blockIdx.x * blockDim.x + threadIdx.x;
  if (p >= NH * NT * NT) return;
  int j = p % NT, i = (p / NT) % NT, h = p / (NT * NT);
  double cyi, cxi, cyj, cxj;
  token_coord(i, cyi, cxi);
  token_coord(j, cyj, cxj);
  float fidx = (float)(((cyi - cyj) + 4.0) * 9.0 + ((cxi - cxj) + 4.0));
  int fl = min(max((int)floorf(fidx), 0), 80);
  int ce = min(max((int)ceilf(fidx), 0), 80);
  float w = fidx - (float)fl;
  float pv = (1.0f - w) * rpb[fl * NH + h] + w * rpb[ce * NH + h];
  int li = (i < 25) ? 0 : ((i < 34) ? 1 : 2);
  pos[p] = pv + ab[li * NH + h];
}

// ---------------- W transpose (once per launch): [256][768] f32 -> [768][256] f16 x3 ----------
__global__ __launch_bounds__(256) void wt_kernel(const float* __restrict__ w0,
                                                 const float* __restrict__ w1,
                                                 const float* __restrict__ w2,
                                                 _Float16* __restrict__ wt) {
  const int bx = blockIdx.x;                 // 36 blocks: 12 per W
  const float* src = bx < 12 ? w0 : (bx < 24 ? w1 : w2);
  _Float16* dst = wt + (size_t)(bx / 12) * QKVN * C;
  const int m0 = (bx % 12) * 64;             // output-row (n) range
  __shared__ _Float16 t[64][264];
  const int tid = threadIdx.x;
  const int p4 = (tid & 15) * 4;
#pragma unroll
  for (int it = 0; it < 16; ++it) {
    int c = it * 16 + (tid >> 4);
    floatx4 v = *(const floatx4*)(src + (size_t)c * QKVN + m0 + p4);
#pragma unroll
    for (int i = 0; i < 4; ++i) t[p4 + i][c] = (_Float16)v[i];
  }
  __syncthreads();
#pragma unroll
  for (int e0 = 0; e0 < 8; ++e0) {
    int e = e0 * 256 + tid;
    int p = e >> 5, c8 = e & 31;
    *(half8v*)(dst + (size_t)(m0 + p) * C + c8 * 8) = *(const half8v*)&t[p][c8 * 8];
  }
}

// ---------------- fused QKV GEMM: persistent-A (64-row tile), n-split 2, single Bs ----------
// LDS = As 33.8 KB + Bs 10.2 KB = 44.0 KB -> 3 blocks/CU (the round-8 occupancy fix).
// Per K-step: write Bs -> barrier -> {issue next B load + MFMA} -> barrier (1-deep overlap,
// Wt is L2-resident). A staged once from raw [C][HW] f32 X (coalesced strided loads,
// conflict-free b128 LDS writes).
__global__ __launch_bounds__(256) void qkv_gemm(const float* __restrict__ X0,
                                                const float* __restrict__ X1,
                                                const float* __restrict__ X2,
                                                const _Float16* __restrict__ Wt,
                                                _Float16* __restrict__ Y0,
                                                _Float16* __restrict__ Y1,
                                                _Float16* __restrict__ Y2,
                                                int mb0, int mb01, int g) {
  __shared__ _Float16 As[64][264];      // 33.8 KB
  __shared__ _Float16 Bs[128][40];      // 10.2 KB

  int mblk = blockIdx.y;
  const int ny = blockIdx.x;            // n-half: tiles ny*3 .. ny*3+2
  const float* X; const _Float16* WtL; _Float16* Y; int HW;
  if (mblk < mb0)       { X = X0; WtL = Wt;                 Y = Y0; HW = 6400; }
  else if (mblk < mb01) { X = X1; WtL = Wt + QKVN * C;      Y = Y1; HW = 1600; mblk -= mb0; }
  else                  { X = X2; WtL = Wt + 2 * QKVN * C;  Y = Y2; HW =  400; mblk -= mb01; }
  const int Mg = g * HW;

  const int tid  = threadIdx.x;
  const int m0   = mblk * 64;
  const int w    = tid >> 6;
  const int lane = tid & 63;
  const int quad = lane >> 4;
  const int mn   = lane & 15;

  // B staging geometry: 512 b128 chunks = 128 n-rows x 4 k-octs, 2 per thread
  int rr[2], k8[2];
#pragma unroll
  for (int u = 0; u < 2; ++u) { int e = u * 256 + tid; rr[u] = e >> 2; k8[u] = e & 3; }

  const int nt0 = ny * 3;
  half8v bpre[2];
  auto PLOAD = [&](int st) {   // st = 0..23 -> (tile nt0+st/8, k0 = (st%8)*32)
    int nt = nt0 + (st >> 3);
    int k0 = (st & 7) * 32;
#pragma unroll
    for (int u = 0; u < 2; ++u)
      bpre[u] = *(const half8v*)(WtL + (size_t)(nt * 128 + rr[u]) * C + k8[u] * 8 + k0);
  };

  PLOAD(0);   // issue first B load before the A-stage (overlaps)

  // ---- stage A once: thread owns row (tid&63), k-octs (tid>>6)+4i
  {
    const int r  = tid & 63;
    const int ob = tid >> 6;
    int gm = min(m0 + r, Mg - 1);
    int bb = gm / HW, pix = gm - bb * HW;
    const float* xb = X + (size_t)bb * C * HW + pix;
#pragma unroll
    for (int i = 0; i < 8; ++i) {
      int oct = ob + 4 * i;
      const float* xp = xb + (size_t)oct * 8 * HW;
      half8v hv;
#pragma unroll
      for (int j = 0; j < 8; ++j) hv[j] = (_Float16)xp[(size_t)j * HW];
      *(half8v*)&As[r][oct * 8] = hv;
    }
  }

  for (int ntl = 0; ntl < 3; ++ntl) {
    floatx4 acc[8] = {};
#pragma unroll
    for (int kk = 0; kk < 8; ++kk) {
      // write current step's B (bpre), make visible (also covers A-stage on first iter)
#pragma unroll
      for (int u = 0; u < 2; ++u) *(half8v*)&Bs[rr[u]][k8[u] * 8] = bpre[u];
      __syncthreads();
      int pst = ntl * 8 + kk + 1;
      if (pst < 24) PLOAD(pst);          // next step's load flies under the MFMAs
      const int k0 = kk * 32;
      half8v a0 = *(const half8v*)&As[w * 16 + mn][k0 + quad * 8];
#pragma unroll
      for (int ni = 0; ni < 8; ++ni) {
        half8v bf = *(const half8v*)&Bs[ni * 16 + mn][quad * 8];
        acc[ni] = __builtin_amdgcn_mfma_f32_16x16x32_f16(a0, bf, acc[ni], 0, 0, 0);
      }
      __syncthreads();                   // readers done before next write
    }

    // epilogue for this n-tile (regs + global stores only)
    const int n0 = (nt0 + ntl) * 128;
    const bool do_norm = (n0 < 512);
#pragma unroll
    for (int r = 0; r < 4; ++r) {
      float s0 = 0.f, s1 = 0.f;
#pragma unroll
      for (int ni = 0; ni < 4; ++ni) { float vv = acc[ni][r]; s0 += vv * vv; }
#pragma unroll
      for (int ni = 4; ni < 8; ++ni) { float vv = acc[ni][r]; s1 += vv * vv; }
      s0 += __shfl_xor(s0, 1); s1 += __shfl_xor(s1, 1);
      s0 += __shfl_xor(s0, 2); s1 += __shfl_xor(s1, 2);
      s0 += __shfl_xor(s0, 4); s1 += __shfl_xor(s1, 4);
      s0 += __shfl_xor(s0, 8); s1 += __shfl_xor(s1, 8);
      float sc0 = do_norm ? (1.f / fmaxf(sqrtf(s0), 1e-12f)) : 1.f;
      float sc1 = do_norm ? (1.f / fmaxf(sqrtf(s1), 1e-12f)) : 1.f;
      int row = m0 + w * 16 + quad * 4 + r;
      if (row < Mg) {
#pragma unroll
        for (int ni = 0; ni < 8; ++ni)
          Y[(size_t)row * QKVN + n0 + ni * 16 + mn] =
              (_Float16)(acc[ni][r] * (ni < 4 ? sc0 : sc1));
      }
    }
  }
}

// ---------------- attention: swapped-operand MFMA version. Block = (b, window); wave = head. ----------------
__device__ inline const _Float16* token_row_ptr(int j, int wy, int wx, int b,
                                                const _Float16* q0, const _Float16* q1,
                                                const _Float16* q2) {
  if (j >= NT) return nullptr;
  int k_, s_, p_, Hl, t; const _Float16* base;
  if (j < 25)      { k_ = 5; s_ = 4; p_ = 2; Hl = 80; t = j;      base = q0; }
  else if (j < 34) { k_ = 3; s_ = 2; p_ = 1; Hl = 40; t = j - 25; base = q1; }
  else             { k_ = 1; s_ = 1; p_ = 0; Hl = 20; t = 0;      base = q2; }
  int ty = t / k_, tx = t % k_;
  int y = wy * s_ + ty - p_;
  int x = wx * s_ + tx - p_;
  if ((unsigned)y >= (unsigned)Hl || (unsigned)x >= (unsigned)Hl) return nullptr;
  return base + ((size_t)b * Hl * Hl + (size_t)y * Hl + x) * QKVN;
}

__global__ __launch_bounds__(256, 4) void attn_kernel(const _Float16* __restrict__ qkv0,
                                                      const _Float16* __restrict__ qkv1,
                                                      const _Float16* __restrict__ qkv2,
                                                      const float* __restrict__ pos,
                                                      _Float16* __restrict__ O) {
  const int blk = blockIdx.x;               // b*NWIN + w
  const int w   = blk % NWIN;
  const int b   = blk / NWIN;
  const int wy = w / 20, wx = w % 20;
  const int tid  = threadIdx.x;
  const int h    = tid >> 6;                // wave = head
  const int lane = tid & 63;
  const int i16  = lane & 15;
  const int q4   = lane >> 4;

  __shared__ __align__(16) _Float16 vrows[48][260];   // V row-major, all heads; rows 35..47 zero

  // --- cooperative V staging: 1536 half8-chunks = 48 rows x 32 chunks over 256 threads
#pragma unroll
  for (int e0 = 0; e0 < 1536; e0 += 256) {
    int e = e0 + tid;
    int j = e >> 5, cc = e & 31;
    half8v val = (half8v)(_Float16)0.f;
    if (j < NT) {
      const _Float16* rp = token_row_ptr(j, wy, wx, b, qkv0, qkv1, qkv2);
      if (rp) val = *(const half8v*)(rp + 512 + cc * 8);
    }
    *(half8v*)&vrows[j][cc * 8] = val;
  }

  // --- Q/K fragments direct from global: tile t rows = tokens t*16 + i16
  half8v qf[3][2], kf[3][2];
#pragma unroll
  for (int t = 0; t < 3; ++t) {
    const _Float16* rp = token_row_ptr(t * 16 + i16, wy, wx, b, qkv0, qkv1, qkv2);
#pragma unroll
    for (int kc = 0; kc < 2; ++kc) {
      if (rp) {
        qf[t][kc] = *(const half8v*)(rp + h * HD + kc * 32 + q4 * 8);
        kf[t][kc] = *(const half8v*)(rp + 256 + h * HD + kc * 32 + q4 * 8);
      } else {
        qf[t][kc] = (half8v)(_Float16)0.f;
        kf[t][kc] = (half8v)(_Float16)0.f;
      }
    }
  }

  // --- swapped QK^T: s[tj][ti][r] = S^T[j=tj*16+q4*4+r][i=ti*16+i16]
  floatx4 s[3][3] = {};
#pragma unroll
  for (int kc = 0; kc < 2; ++kc)
#pragma unroll
    for (int tj = 0; tj < 3; ++tj)
#pragma unroll
      for (int ti = 0; ti < 3; ++ti)
        s[tj][ti] = __builtin_amdgcn_mfma_f32_16x16x32_f16(kf[tj][kc], qf[ti][kc], s[tj][ti], 0, 0, 0);

  // --- pos bias + tile-pad mask (j >= NT -> -inf; tj=0 rows are never masked so max stays finite)
#pragma unroll
  for (int tj = 0; tj < 3; ++tj)
#pragma unroll
    for (int ti = 0; ti < 3; ++ti)
#pragma unroll
      for (int r = 0; r < 4; ++r) {
        int j = tj * 16 + q4 * 4 + r;
        int i = ti * 16 + i16;
        if (j < NT) { if (i < NT) s[tj][ti][r] += pos[(h * NT + i) * NT + j]; }
        else s[tj][ti][r] = -INFINITY;
      }

  // --- in-register softmax over j per query i (col i16): 12 local regs + shfl_xor 16/32
  half4v pa[3][3];   // [tj][ti] = A-frag of P for PV (16x16x16 layout)
#pragma unroll
  for (int ti = 0; ti < 3; ++ti) {
    float m = s[0][ti][0];
#pragma unroll
    for (int tj = 0; tj < 3; ++tj)
#pragma unroll
      for (int r = 0; r < 4; ++r) m = fmaxf(m, s[tj][ti][r]);
    m = fmaxf(m, __shfl_xor(m, 16));
    m = fmaxf(m, __shfl_xor(m, 32));
    float sum = 0.f;
#pragma unroll
    for (int tj = 0; tj < 3; ++tj)
#pragma unroll
      for (int r = 0; r < 4; ++r) { float e = expf(s[tj][ti][r] - m); s[tj][ti][r] = e; sum += e; }
    sum += __shfl_xor(sum, 16);
    sum += __shfl_xor(sum, 32);
    float inv = 1.f / sum;
#pragma unroll
    for (int tj = 0; tj < 3; ++tj)
#pragma unroll
      for (int r = 0; r < 4; ++r) pa[tj][ti][r] = (_Float16)(s[tj][ti][r] * inv);
  }

  __syncthreads();   // vrows ready for all waves

  // --- V B-frags for 16x16x16: lane holds V[j=tj*16+q4*4+kk][d=n*16+i16] (this head's cols)
  half4v vb[3][4];
#pragma unroll
  for (int tj = 0; tj < 3; ++tj)
#pragma unroll
    for (int n = 0; n < 4; ++n)
#pragma unroll
      for (int kk = 0; kk < 4; ++kk)
        vb[tj][n][kk] = vrows[tj * 16 + q4 * 4 + kk][h * HD + n * 16 + i16];

  // --- PV: O[i][d] accumulated over 3 j-chunks of 16; C layout row=q4*4+r (i), col=i16 (d)
  const size_t obase = ((size_t)(b * NWIN + w) * NT) * C + h * HD;
#pragma unroll
  for (int ti = 0; ti < 3; ++ti) {
    floatx4 o[4] = {};
#pragma unroll
    for (int tj = 0; tj < 3; ++tj)
#pragma unroll
      for (int n = 0; n < 4; ++n)
        o[n] = __builtin_amdgcn_mfma_f32_16x16x16f16(pa[tj][ti], vb[tj][n], o[n], 0, 0, 0);
#pragma unroll
    for (int r = 0; r < 4; ++r) {
      int i = ti * 16 + q4 * 4 + r;
      if (i < NT) {
#pragma unroll
        for (int n = 0; n < 4; ++n)
          O[obase + (size_t)i * C + n * 16 + i16] = (_Float16)o[n][r];
      }
    }
  }
}

// ---------------- proj GEMM (f16 MFMA, reg-prefetch) + bias, transposed store ----------------
__global__ __launch_bounds__(256) void proj_gemm(const _Float16* __restrict__ A,  // (Mg, 256) f16 row-major
                                                 const float* __restrict__ W,     // (256, 256) row-major
                                                 const float* __restrict__ bias,
                                                 float* __restrict__ Yt, int Mg) {
  __shared__ __align__(16) char smem[128 * 69 * 4];   // max(As+Bs = 15360, Cs = 35328)
  _Float16 (*As)[40] = (_Float16(*)[40])smem;
  _Float16 (*Bs)[40] = (_Float16(*)[40])(smem + 128 * 40 * 2);
  float    (*Cs)[69] = (float(*)[69])smem;

  const int tid  = threadIdx.x;
  const int m0   = blockIdx.x * 128;
  const int n0   = blockIdx.y * 64;
  const int w    = tid >> 6;
  const int lane = tid & 63;
  const int quad = lane >> 4;
  const int mn   = lane & 15;

  int aM[2], aK8[2], aRow[2];
#pragma unroll
  for (int u = 0; u < 2; ++u) {
    int e = u * 256 + tid;           // 512 units: 128 m x 4 k-octs
    aM[u] = e >> 2; aK8[u] = e & 3;
    aRow[u] = min(m0 + aM[u], Mg - 1);
  }

  half8v apre[2]; float bpre[8];
  auto PLOAD = [&](int k0) {
#pragma unroll
    for (int u = 0; u < 2; ++u)
      apre[u] = *(const half8v*)&A[(size_t)aRow[u] * C + k0 + 8 * aK8[u]];
    const float* wp = W + (size_t)(k0 + w * 8) * C + n0 + lane;
#pragma unroll
    for (int j = 0; j < 8; ++j) bpre[j] = wp[(size_t)j * C];
  };

  PLOAD(0);
  floatx4 acc[2][4] = {};
  for (int k0 = 0; k0 < C; k0 += 32) {
#pragma unroll
    for (int u = 0; u < 2; ++u) *(half8v*)&As[aM[u]][8 * aK8[u]] = apre[u];
    {
      half8v hv;
#pragma unroll
      for (int j = 0; j < 8; ++j) hv[j] = (_Float16)bpre[j];
      *(half8v*)&Bs[lane][w * 8] = hv;
    }
    __syncthreads();
    if (k0 + 32 < C) PLOAD(k0 + 32);   // prefetch next K-step under MFMA
    half8v a0 = *(const half8v*)&As[w * 32 + mn][quad * 8];
    half8v a1 = *(const half8v*)&As[w * 32 + 16 + mn][quad * 8];
#pragma unroll
    for (int ni = 0; ni < 4; ++ni) {
      half8v bf = *(const half8v*)&Bs[ni * 16 + mn][quad * 8];
      acc[0][ni] = __builtin_amdgcn_mfma_f32_16x16x32_f16(a0, bf, acc[0][ni], 0, 0, 0);
      acc[1][ni] = __builtin_amdgcn_mfma_f32_16x16x32_f16(a1, bf, acc[1][ni], 0, 0, 0);
    }
    __syncthreads();   // also protects As/Bs before Cs aliasing overwrite
  }

  // epilogue: bias add into Cs, then transposed coalesced store
#pragma unroll
  for (int mi = 0; mi < 2; ++mi)
#pragma unroll
    for (int r = 0; r < 4; ++r)
#pragma unroll
      for (int ni = 0; ni < 4; ++ni)
        Cs[w * 32 + mi * 16 + quad * 4 + r][ni * 16 + mn] =
            acc[mi][ni][r] + bias[n0 + ni * 16 + mn];
  __syncthreads();
#pragma unroll
  for (int u = 0; u < 32; ++u) {
    int e = u * 256 + tid;            // 8192 elems: 128 m x 64 n
    int ml = e & 127, cl = e >> 7;
    int m = m0 + ml;
    if (m < Mg) {
      int bb = m / RPB;
      int r = m - bb * RPB;
      Yt[((size_t)bb * C + n0 + cl) * RPB + r] = Cs[ml][cl];
    }
  }
}

// ---------------- fused fold: all 3 levels in one launch ----------------
__global__ __launch_bounds__(256) void fold_all(const float* __restrict__ Yt,
                                                float* __restrict__ out, int b0,
                                                int tot0, int tot01, int tot012) {
  int idx = blockIdx.x * 256 + threadIdx.x;
  if (idx >= tot012) return;
  int k_, s_, p_, H_, toff, local;
  float* dst;
  if (idx < tot0) {
    k_ = 5; s_ = 4; p_ = 2; H_ = 80; toff = 0;  local = idx;
    dst = out + (size_t)b0 * C * 6400;
  } else if (idx < tot01) {
    k_ = 3; s_ = 2; p_ = 1; H_ = 40; toff = 25; local = idx - tot0;
    dst = out + (size_t)B * C * 6400 + (size_t)b0 * C * 1600;
  } else {
    k_ = 1; s_ = 1; p_ = 0; H_ = 20; toff = 34; local = idx - tot01;
    dst = out + (size_t)B * C * (6400 + 1600) + (size_t)b0 * C * 400;
  }
  int x = local % H_;
  int y = (local / H_) % H_;
  int c = (local / (H_ * H_)) % C;
  int b = local / (C * H_ * H_);
  int py = y + p_, px = x + p_;
  int ay = py - k_ + 1;
  int wy_lo = ay <= 0 ? 0 : (ay + s_ - 1) / s_;
  int wy_hi = min(19, py / s_);
  int ax = px - k_ + 1;
  int wx_lo = ax <= 0 ? 0 : (ax + s_ - 1) / s_;
  int wx_hi = min(19, px / s_);
  const float* base = Yt + ((size_t)b * C + c) * RPB;
  float acc = 0.f;
  for (int wy = wy_lo; wy <= wy_hi; ++wy) {
    int tyy = py - wy * s_;
    for (int wx = wx_lo; wx <= wx_hi; ++wx) {
      int txx = px - wx * s_;
      acc += base[(wy * 20 + wx) * NT + toff + tyy * k_ + txx];
    }
  }
  dst[local] = acc;
}

} // namespace

extern "C" void kernel_launch(void* const* d_in, const int* in_sizes, int n_in,
                              void* d_out, int out_size, void* d_ws, size_t ws_size,
                              hipStream_t stream) {
  const float* x0    = (const float*)d_in[0];
  const float* x1    = (const float*)d_in[1];
  const float* x2    = (const float*)d_in[2];
  const float* wq0   = (const float*)d_in[3];
  const float* wq1   = (const float*)d_in[4];
  const float* wq2   = (const float*)d_in[5];
  const float* wproj = (const float*)d_in[6];
  const float* bproj = (const float*)d_in[7];
  const float* rpb   = (const float*)d_in[8];
  const float* ab    = (const float*)d_in[9];
  float* out = (float*)d_out;

  // largest batch-group g in {8,4,2,1}; yt aliases the (dead-by-then) qkv region.
  int g = 8;
  while (g > 1 && POS_B + WT_B + (size_t)g * PBA_B > ws_size) g >>= 1;

  char* ws = (char*)d_ws;
  float*    posb  = (float*)ws;
  _Float16* wt    = (_Float16*)(ws + POS_B);
  char*     base  = ws + POS_B + WT_B;
  _Float16* qkv0g = (_Float16*)base;
  _Float16* qkv1g = qkv0g + (size_t)g * 6400 * QKVN;
  _Float16* qkv2g = qkv1g + (size_t)g * 1600 * QKVN;
  float*    yt    = (float*)base;                       // aliases qkv (dead after attn)
  _Float16* oatt  = (_Float16*)(base + (size_t)g * YT_B);

  pos_kernel<<<(NH * NT * NT + 255) / 256, 256, 0, stream>>>(rpb, ab, posb);
  wt_kernel<<<36, 256, 0, stream>>>(wq0, wq1, wq2, wt);

  const int mb0 = (g * 6400 + 63) / 64;
  const int mb1 = (g * 1600 + 63) / 64;
  const int mb2 = (g *  400 + 63) / 64;

  for (int b0 = 0; b0 < B; b0 += g) {
    const float* x0g = x0 + (size_t)b0 * C * 6400;
    const float* x1g = x1 + (size_t)b0 * C * 1600;
    const float* x2g = x2 + (size_t)b0 * C * 400;

    qkv_gemm<<<dim3(2, mb0 + mb1 + mb2), 256, 0, stream>>>(
        x0g, x1g, x2g, wt, qkv0g, qkv1g, qkv2g, mb0, mb0 + mb1, g);

    attn_kernel<<<g * NWIN, 256, 0, stream>>>(qkv0g, qkv1g, qkv2g, posb, oatt);

    proj_gemm<<<dim3((g * RPB + 127) / 128, C / 64), 256, 0, stream>>>(oatt, wproj, bproj, yt, g * RPB);

    const int tot0  = g * C * 6400;
    const int tot01 = tot0 + g * C * 1600;
    const int tot012 = tot01 + g * C * 400;
    fold_all<<<(tot012 + 255) / 256, 256, 0, stream>>>(yt, out, b0, tot0, tot01, tot012);
  }
}